// Round 1
// baseline (2157.742 us; speedup 1.0000x reference)
//
#include <hip/hip_runtime.h>
#include <hip/hip_bf16.h>
#include <stdint.h>

// Problem constants
#define BATCH   512
#define DIMS    512
#define NCLS    50000
#define KSUB    3
#define NW      150000   // NCLS*KSUB rows of weights
#define SCALE_F 64.0f
#define EPS_F   1e-12f

typedef __bf16 bf16x8 __attribute__((ext_vector_type(8)));
typedef __bf16 bf16x4 __attribute__((ext_vector_type(4)));
typedef float  f32x4  __attribute__((ext_vector_type(4)));

// async global->LDS, 16B per lane. LDS dest is wave-uniform base + lane*16.
__device__ __forceinline__ void gld16(const void* g, void* l) {
  __builtin_amdgcn_global_load_lds((const __attribute__((address_space(1))) void*)g,
                                   (__attribute__((address_space(3))) void*)l, 16, 0, 0);
}

// ---------------------------------------------------------------------------
// Prepass: L2-normalize rows in fp32, cast to bf16.
// Rows 0..NW-1 -> weights, rows NW..NW+BATCH-1 -> input. One wave per row.
// ---------------------------------------------------------------------------
__global__ __launch_bounds__(256) void normalize_all(
    const float* __restrict__ w, const float* __restrict__ x,
    __bf16* __restrict__ wb, __bf16* __restrict__ xb) {
  int wave = threadIdx.x >> 6, lane = threadIdx.x & 63;
  int r = blockIdx.x * 4 + wave;
  if (r >= NW + BATCH) return;
  const float* src;
  __bf16* dst;
  if (r < NW) { src = w + (size_t)r * DIMS; dst = wb + (size_t)r * DIMS; }
  else        { int r2 = r - NW; src = x + (size_t)r2 * DIMS; dst = xb + (size_t)r2 * DIMS; }

  const float4* rp = (const float4*)src;
  float4 v0 = rp[lane];
  float4 v1 = rp[lane + 64];
  float s = v0.x*v0.x + v0.y*v0.y + v0.z*v0.z + v0.w*v0.w
          + v1.x*v1.x + v1.y*v1.y + v1.z*v1.z + v1.w*v1.w;
  #pragma unroll
  for (int m = 1; m < 64; m <<= 1) s += __shfl_xor(s, m, 64);
  float inv = 1.0f / fmaxf(sqrtf(s), EPS_F);

  bf16x4 o0, o1;
  o0[0] = (__bf16)(v0.x * inv); o0[1] = (__bf16)(v0.y * inv);
  o0[2] = (__bf16)(v0.z * inv); o0[3] = (__bf16)(v0.w * inv);
  o1[0] = (__bf16)(v1.x * inv); o1[1] = (__bf16)(v1.y * inv);
  o1[2] = (__bf16)(v1.z * inv); o1[3] = (__bf16)(v1.w * inv);
  bf16x4* wp = (bf16x4*)dst;
  wp[lane]      = o0;
  wp[lane + 64] = o1;
}

// ---------------------------------------------------------------------------
// GEMM: out[b][c] = 64 * max_{k<3} ( xb[b] . wb[3c+k] ), bf16 MFMA.
// BM=128 rows, BN=192 cos-cols (=64 classes), BK=32. 4 waves, 2x2, each wave
// 64x96 via 4x6 tiles of mfma_f32_16x16x32_bf16. m97-style global_load_lds
// staging. Epilogue: per-wave LDS transpose (pitch 100) -> max3 -> store.
// ---------------------------------------------------------------------------
#define BM 128
#define BN 192
#define BK 32

__global__ __launch_bounds__(256, 2) void gemm_max3(
    const __bf16* __restrict__ xb, const __bf16* __restrict__ wb,
    float* __restrict__ out) {
  __shared__ __align__(16) char smem[25600];
  unsigned short* As = (unsigned short*)smem;           // [128][32] bf16, 8 KB
  unsigned short* Bs = (unsigned short*)(smem + 8192);  // [192][32] bf16, 12 KB

  const int tid  = threadIdx.x;
  const int wave = tid >> 6;
  const int lane = tid & 63;
  const int bx   = blockIdx.x;
  const int mt   = bx & 3;        // m-fastest: 4 consecutive blocks share B tile (LLC)
  const int ct   = bx >> 2;
  const int m0   = mt * BM;
  const int n0   = ct * BN;       // w-row base (cos column base)

  const int wm   = wave & 1;      // row half (64 rows)
  const int wn   = wave >> 1;     // col half (96 cos cols)
  const int l15  = lane & 15;
  const int quad = lane >> 4;

  // staging decode: each lane moves 16B; 4 lanes per 64B row-chunk
  const int srow = lane >> 2;        // 0..15
  const int scol = (lane & 3) << 3;  // element offset 0,8,16,24

  f32x4 acc[4][6] = {};

  for (int kk = 0; kk < DIMS; kk += BK) {
    // ---- stage A (8 chunks) + B (12 chunks); 5 wave-instrs per wave ----
    #pragma unroll
    for (int s5 = 0; s5 < 5; ++s5) {
      int s = wave * 5 + s5;  // wave-uniform
      if (s < 8) {
        int row = s * 16 + srow;
        gld16(xb + (size_t)(m0 + row) * DIMS + kk + scol, As + s * 512);
      } else {
        int t = s - 8;
        int grow = n0 + t * 16 + srow;
        if (grow > NW - 1) grow = NW - 1;   // tail clamp (stores masked)
        gld16(wb + (size_t)grow * DIMS + kk + scol, Bs + t * 512);
      }
    }
    __syncthreads();

    // ---- fragments + MFMA ----
    bf16x8 a[4], bfr[6];
    #pragma unroll
    for (int i = 0; i < 4; ++i)
      a[i] = *(const bf16x8*)(As + (wm * 64 + i * 16 + l15) * 32 + quad * 8);
    #pragma unroll
    for (int j = 0; j < 6; ++j)
      bfr[j] = *(const bf16x8*)(Bs + (wn * 96 + j * 16 + l15) * 32 + quad * 8);
    #pragma unroll
    for (int i = 0; i < 4; ++i)
      #pragma unroll
      for (int j = 0; j < 6; ++j)
        acc[i][j] = __builtin_amdgcn_mfma_f32_16x16x32_bf16(a[i], bfr[j], acc[i][j], 0, 0, 0);
    __syncthreads();
  }

  // ---- epilogue: per-wave LDS transpose, max over groups of 3 cols ----
  // scr: 16 rows x 100 floats (pad: pitch 100 -> 2-way bank conflicts = free)
  float* scr = (float*)smem + wave * 1600;
  const int rl   = lane >> 2;   // read row 0..15
  const int gblk = lane & 3;    // 8-group block
  #pragma unroll 1
  for (int i = 0; i < 4; ++i) {
    #pragma unroll
    for (int j = 0; j < 6; ++j)
      #pragma unroll
      for (int r = 0; r < 4; ++r)
        scr[(quad * 4 + r) * 100 + j * 16 + l15] = acc[i][j][r] * SCALE_F;
    __asm__ volatile("s_waitcnt lgkmcnt(0)" ::: "memory");

    float f[24];
    const float4* srcp = (const float4*)(scr + rl * 100 + gblk * 24);
    #pragma unroll
    for (int t = 0; t < 6; ++t) *(float4*)(f + 4 * t) = srcp[t];

    float o[8];
    #pragma unroll
    for (int t = 0; t < 8; ++t)
      o[t] = fmaxf(f[3 * t], fmaxf(f[3 * t + 1], f[3 * t + 2]));

    int brow = m0 + wm * 64 + i * 16 + rl;
    int cls0 = ct * 64 + wn * 32 + gblk * 8;
    float* op = out + (size_t)brow * NCLS + cls0;
    if (cls0 + 8 <= NCLS) {
      float4 s0 = {o[0], o[1], o[2], o[3]};
      float4 s1 = {o[4], o[5], o[6], o[7]};
      *(float4*)op = s0;
      *(float4*)(op + 4) = s1;
    } else {
      #pragma unroll
      for (int t = 0; t < 8; ++t)
        if (cls0 + t < NCLS) op[t] = o[t];
    }
    __asm__ volatile("s_waitcnt lgkmcnt(0)" ::: "memory");
  }
}

// ---------------------------------------------------------------------------
// Fixup: exact fp32 recompute of the 3 sub-center cosines at the label column.
// One wave per batch row.
// ---------------------------------------------------------------------------
__device__ __forceinline__ float d4(float4 a, float4 b) {
  return a.x * b.x + a.y * b.y + a.z * b.z + a.w * b.w;
}

__global__ __launch_bounds__(64) void fix_labels(
    const float* __restrict__ x, const int* __restrict__ label,
    const float* __restrict__ w, const float* __restrict__ margins,
    float* __restrict__ out) {
  int b = blockIdx.x;
  int lane = threadIdx.x;
  int c = label[b];
  const float4* xr = (const float4*)(x + (size_t)b * DIMS);
  const float4* w0 = (const float4*)(w + (size_t)(3 * c + 0) * DIMS);
  const float4* w1 = (const float4*)(w + (size_t)(3 * c + 1) * DIMS);
  const float4* w2 = (const float4*)(w + (size_t)(3 * c + 2) * DIMS);

  float xx = 0, n0 = 0, n1 = 0, n2 = 0, p0 = 0, p1 = 0, p2 = 0;
  #pragma unroll
  for (int t = 0; t < 2; ++t) {
    int i = lane + t * 64;
    float4 xv = xr[i], a0 = w0[i], a1 = w1[i], a2 = w2[i];
    xx += d4(xv, xv);
    n0 += d4(a0, a0); n1 += d4(a1, a1); n2 += d4(a2, a2);
    p0 += d4(xv, a0); p1 += d4(xv, a1); p2 += d4(xv, a2);
  }
  #pragma unroll
  for (int m = 1; m < 64; m <<= 1) {
    xx += __shfl_xor(xx, m, 64);
    n0 += __shfl_xor(n0, m, 64); n1 += __shfl_xor(n1, m, 64); n2 += __shfl_xor(n2, m, 64);
    p0 += __shfl_xor(p0, m, 64); p1 += __shfl_xor(p1, m, 64); p2 += __shfl_xor(p2, m, 64);
  }
  if (lane == 0) {
    float rx = 1.0f / fmaxf(sqrtf(xx), EPS_F);
    float r0 = 1.0f / fmaxf(sqrtf(n0), EPS_F);
    float r1 = 1.0f / fmaxf(sqrtf(n1), EPS_F);
    float r2 = 1.0f / fmaxf(sqrtf(n2), EPS_F);
    float c0 = p0 * rx * r0, c1 = p1 * rx * r1, c2 = p2 * rx * r2;
    float tgt = fmaxf(c0, fmaxf(c1, c2));
    float shift = 0.5f * (fabsf(c0 - c1) + fabsf(c0 - c2));
    float wm = margins[c] * (1.0f + shift);
    out[(size_t)b * NCLS + c] = SCALE_F * (tgt - wm);
  }
}

// ---------------------------------------------------------------------------
extern "C" void kernel_launch(void* const* d_in, const int* in_sizes, int n_in,
                              void* d_out, int out_size, void* d_ws, size_t ws_size,
                              hipStream_t stream) {
  const float* input   = (const float*)d_in[0];
  const int*   label   = (const int*)d_in[1];
  const float* weights = (const float*)d_in[2];
  const float* margins = (const float*)d_in[3];
  float* out = (float*)d_out;

  __bf16* w_bf = (__bf16*)d_ws;                       // 150000*512 bf16 = 153.6 MB
  __bf16* x_bf = w_bf + (size_t)NW * DIMS;            // 512*512 bf16

  // 1) normalize+cast all rows (150512 rows, 4 per block)
  normalize_all<<<(NW + BATCH) / 4, 256, 0, stream>>>(weights, input, w_bf, x_bf);
  // 2) GEMM + max3 epilogue: grid = 4 m-tiles (fastest) x 782 class-tiles
  gemm_max3<<<4 * ((NCLS * KSUB + BN - 1) / BN), 256, 0, stream>>>(x_bf, w_bf, out);
  // 3) exact fp32 fixup of label columns
  fix_labels<<<BATCH, 64, 0, stream>>>(input, label, weights, margins, out);
}

// Round 2
// 577.042 us; speedup vs baseline: 3.7393x; 3.7393x over previous
//
#include <hip/hip_runtime.h>
#include <hip/hip_bf16.h>
#include <stdint.h>

// Problem constants
#define BATCH   512
#define DIMS    512
#define NCLS    50000
#define KSUB    3
#define NW      150000   // NCLS*KSUB rows of weights
#define SCALE_F 64.0f
#define EPS_F   1e-12f

typedef __bf16 bf16x8 __attribute__((ext_vector_type(8)));
typedef __bf16 bf16x4 __attribute__((ext_vector_type(4)));
typedef float  f32x4  __attribute__((ext_vector_type(4)));

// async global->LDS, 16B per lane. LDS dest is wave-uniform base + lane*16.
__device__ __forceinline__ void gld16(const void* g, void* l) {
  __builtin_amdgcn_global_load_lds((const __attribute__((address_space(1))) void*)g,
                                   (__attribute__((address_space(3))) void*)l, 16, 0, 0);
}

// ---------------------------------------------------------------------------
// Prepass: L2-normalize rows in fp32, cast to bf16.
// Rows 0..NW-1 -> weights, rows NW..NW+BATCH-1 -> input. One wave per row.
// ---------------------------------------------------------------------------
__global__ __launch_bounds__(256) void normalize_all(
    const float* __restrict__ w, const float* __restrict__ x,
    __bf16* __restrict__ wb, __bf16* __restrict__ xb) {
  int wave = threadIdx.x >> 6, lane = threadIdx.x & 63;
  int r = blockIdx.x * 4 + wave;
  if (r >= NW + BATCH) return;
  const float* src;
  __bf16* dst;
  if (r < NW) { src = w + (size_t)r * DIMS; dst = wb + (size_t)r * DIMS; }
  else        { int r2 = r - NW; src = x + (size_t)r2 * DIMS; dst = xb + (size_t)r2 * DIMS; }

  const float4* rp = (const float4*)src;
  float4 v0 = rp[lane];
  float4 v1 = rp[lane + 64];
  float s = v0.x*v0.x + v0.y*v0.y + v0.z*v0.z + v0.w*v0.w
          + v1.x*v1.x + v1.y*v1.y + v1.z*v1.z + v1.w*v1.w;
  #pragma unroll
  for (int m = 1; m < 64; m <<= 1) s += __shfl_xor(s, m, 64);
  float inv = 1.0f / fmaxf(sqrtf(s), EPS_F);

  bf16x4 o0, o1;
  o0[0] = (__bf16)(v0.x * inv); o0[1] = (__bf16)(v0.y * inv);
  o0[2] = (__bf16)(v0.z * inv); o0[3] = (__bf16)(v0.w * inv);
  o1[0] = (__bf16)(v1.x * inv); o1[1] = (__bf16)(v1.y * inv);
  o1[2] = (__bf16)(v1.z * inv); o1[3] = (__bf16)(v1.w * inv);
  bf16x4* wp = (bf16x4*)dst;
  wp[lane]      = o0;
  wp[lane + 64] = o1;
}

// ---------------------------------------------------------------------------
// GEMM: out[b][c] = 64 * max_{k<3} ( xb[b] . wb[3c+k] ), bf16 MFMA.
// BM=128 rows, BN=192 cos-cols (=64 classes), BK=32. 4 waves, 2x2, each wave
// 64x96 via 4x6 tiles of mfma_f32_16x16x32_bf16. m97-style global_load_lds
// staging. Epilogue: per-wave LDS transpose (pitch 100) -> max3 -> store.
// NOTE: epilogue i-loop MUST be fully unrolled — runtime indexing of acc[]
// demotes it to scratch (R1: VGPR=44, 8.5 GB HBM traffic, MfmaUtil 1.8%).
// ---------------------------------------------------------------------------
#define BM 128
#define BN 192
#define BK 32

__global__ __launch_bounds__(256, 2) void gemm_max3(
    const __bf16* __restrict__ xb, const __bf16* __restrict__ wb,
    float* __restrict__ out) {
  __shared__ __align__(16) char smem[25600];
  unsigned short* As = (unsigned short*)smem;           // [128][32] bf16, 8 KB
  unsigned short* Bs = (unsigned short*)(smem + 8192);  // [192][32] bf16, 12 KB

  const int tid  = threadIdx.x;
  const int wave = tid >> 6;
  const int lane = tid & 63;
  const int bx   = blockIdx.x;
  const int mt   = bx & 3;        // m-fastest: 4 consecutive blocks share B tile (LLC)
  const int ct   = bx >> 2;
  const int m0   = mt * BM;
  const int n0   = ct * BN;       // w-row base (cos column base)

  const int wm   = wave & 1;      // row half (64 rows)
  const int wn   = wave >> 1;     // col half (96 cos cols)
  const int l15  = lane & 15;
  const int quad = lane >> 4;

  // staging decode: each lane moves 16B; 4 lanes per 64B row-chunk
  const int srow = lane >> 2;        // 0..15
  const int scol = (lane & 3) << 3;  // element offset 0,8,16,24

  f32x4 acc[4][6] = {};

  for (int kk = 0; kk < DIMS; kk += BK) {
    // ---- stage A (8 chunks) + B (12 chunks); 5 wave-instrs per wave ----
    #pragma unroll
    for (int s5 = 0; s5 < 5; ++s5) {
      int s = wave * 5 + s5;  // wave-uniform
      if (s < 8) {
        int row = s * 16 + srow;
        gld16(xb + (size_t)(m0 + row) * DIMS + kk + scol, As + s * 512);
      } else {
        int t = s - 8;
        int grow = n0 + t * 16 + srow;
        if (grow > NW - 1) grow = NW - 1;   // tail clamp (stores masked)
        gld16(wb + (size_t)grow * DIMS + kk + scol, Bs + t * 512);
      }
    }
    __syncthreads();

    // ---- fragments + MFMA ----
    bf16x8 a[4], bfr[6];
    #pragma unroll
    for (int i = 0; i < 4; ++i)
      a[i] = *(const bf16x8*)(As + (wm * 64 + i * 16 + l15) * 32 + quad * 8);
    #pragma unroll
    for (int j = 0; j < 6; ++j)
      bfr[j] = *(const bf16x8*)(Bs + (wn * 96 + j * 16 + l15) * 32 + quad * 8);
    #pragma unroll
    for (int i = 0; i < 4; ++i)
      #pragma unroll
      for (int j = 0; j < 6; ++j)
        acc[i][j] = __builtin_amdgcn_mfma_f32_16x16x32_bf16(a[i], bfr[j], acc[i][j], 0, 0, 0);
    __syncthreads();
  }

  // ---- epilogue: per-wave LDS transpose, max over groups of 3 cols ----
  // scr: 16 rows x 100 floats (pad: pitch 100 -> 2-way bank conflicts = free)
  float* scr = (float*)smem + wave * 1600;
  const int rl   = lane >> 2;   // read row 0..15
  const int gblk = lane & 3;    // 8-group block
  #pragma unroll
  for (int i = 0; i < 4; ++i) {   // FULL unroll: acc[] must stay in registers
    #pragma unroll
    for (int j = 0; j < 6; ++j)
      #pragma unroll
      for (int r = 0; r < 4; ++r)
        scr[(quad * 4 + r) * 100 + j * 16 + l15] = acc[i][j][r] * SCALE_F;
    __asm__ volatile("s_waitcnt lgkmcnt(0)" ::: "memory");

    float f[24];
    const float4* srcp = (const float4*)(scr + rl * 100 + gblk * 24);
    #pragma unroll
    for (int t = 0; t < 6; ++t) *(float4*)(f + 4 * t) = srcp[t];

    float o[8];
    #pragma unroll
    for (int t = 0; t < 8; ++t)
      o[t] = fmaxf(f[3 * t], fmaxf(f[3 * t + 1], f[3 * t + 2]));

    int brow = m0 + wm * 64 + i * 16 + rl;
    int cls0 = ct * 64 + wn * 32 + gblk * 8;
    float* op = out + (size_t)brow * NCLS + cls0;
    if (cls0 + 8 <= NCLS) {
      float4 s0 = {o[0], o[1], o[2], o[3]};
      float4 s1 = {o[4], o[5], o[6], o[7]};
      *(float4*)op = s0;
      *(float4*)(op + 4) = s1;
    } else {
      #pragma unroll
      for (int t = 0; t < 8; ++t)
        if (cls0 + t < NCLS) op[t] = o[t];
    }
    __asm__ volatile("s_waitcnt lgkmcnt(0)" ::: "memory");
  }
}

// ---------------------------------------------------------------------------
// Fixup: exact fp32 recompute of the 3 sub-center cosines at the label column.
// One wave per batch row.
// ---------------------------------------------------------------------------
__device__ __forceinline__ float d4(float4 a, float4 b) {
  return a.x * b.x + a.y * b.y + a.z * b.z + a.w * b.w;
}

__global__ __launch_bounds__(64) void fix_labels(
    const float* __restrict__ x, const int* __restrict__ label,
    const float* __restrict__ w, const float* __restrict__ margins,
    float* __restrict__ out) {
  int b = blockIdx.x;
  int lane = threadIdx.x;
  int c = label[b];
  const float4* xr = (const float4*)(x + (size_t)b * DIMS);
  const float4* w0 = (const float4*)(w + (size_t)(3 * c + 0) * DIMS);
  const float4* w1 = (const float4*)(w + (size_t)(3 * c + 1) * DIMS);
  const float4* w2 = (const float4*)(w + (size_t)(3 * c + 2) * DIMS);

  float xx = 0, n0 = 0, n1 = 0, n2 = 0, p0 = 0, p1 = 0, p2 = 0;
  #pragma unroll
  for (int t = 0; t < 2; ++t) {
    int i = lane + t * 64;
    float4 xv = xr[i], a0 = w0[i], a1 = w1[i], a2 = w2[i];
    xx += d4(xv, xv);
    n0 += d4(a0, a0); n1 += d4(a1, a1); n2 += d4(a2, a2);
    p0 += d4(xv, a0); p1 += d4(xv, a1); p2 += d4(xv, a2);
  }
  #pragma unroll
  for (int m = 1; m < 64; m <<= 1) {
    xx += __shfl_xor(xx, m, 64);
    n0 += __shfl_xor(n0, m, 64); n1 += __shfl_xor(n1, m, 64); n2 += __shfl_xor(n2, m, 64);
    p0 += __shfl_xor(p0, m, 64); p1 += __shfl_xor(p1, m, 64); p2 += __shfl_xor(p2, m, 64);
  }
  if (lane == 0) {
    float rx = 1.0f / fmaxf(sqrtf(xx), EPS_F);
    float r0 = 1.0f / fmaxf(sqrtf(n0), EPS_F);
    float r1 = 1.0f / fmaxf(sqrtf(n1), EPS_F);
    float r2 = 1.0f / fmaxf(sqrtf(n2), EPS_F);
    float c0 = p0 * rx * r0, c1 = p1 * rx * r1, c2 = p2 * rx * r2;
    float tgt = fmaxf(c0, fmaxf(c1, c2));
    float shift = 0.5f * (fabsf(c0 - c1) + fabsf(c0 - c2));
    float wm = margins[c] * (1.0f + shift);
    out[(size_t)b * NCLS + c] = SCALE_F * (tgt - wm);
  }
}

// ---------------------------------------------------------------------------
extern "C" void kernel_launch(void* const* d_in, const int* in_sizes, int n_in,
                              void* d_out, int out_size, void* d_ws, size_t ws_size,
                              hipStream_t stream) {
  const float* input   = (const float*)d_in[0];
  const int*   label   = (const int*)d_in[1];
  const float* weights = (const float*)d_in[2];
  const float* margins = (const float*)d_in[3];
  float* out = (float*)d_out;

  __bf16* w_bf = (__bf16*)d_ws;                       // 150000*512 bf16 = 153.6 MB
  __bf16* x_bf = w_bf + (size_t)NW * DIMS;            // 512*512 bf16

  // 1) normalize+cast all rows (150512 rows, 4 per block)
  normalize_all<<<(NW + BATCH) / 4, 256, 0, stream>>>(weights, input, w_bf, x_bf);
  // 2) GEMM + max3 epilogue: grid = 4 m-tiles (fastest) x 782 class-tiles
  gemm_max3<<<4 * ((NCLS * KSUB + BN - 1) / BN), 256, 0, stream>>>(x_bf, w_bf, out);
  // 3) exact fp32 fixup of label columns
  fix_labels<<<BATCH, 64, 0, stream>>>(input, label, weights, margins, out);
}